// Round 1
// baseline (654.483 us; speedup 1.0000x reference)
//
#include <hip/hip_runtime.h>
#include <hip/hip_bf16.h>
#include <math.h>

#define B_ 4
#define S_ 2048
#define D_ 2048
#define NH_ 16
#define NKV_ 4
#define HD_ 128

typedef short bf16x8 __attribute__((ext_vector_type(8)));
typedef float f32x4 __attribute__((ext_vector_type(4)));
typedef __hip_bfloat16 bf16;

// ---------------- f32 -> bf16 conversion (4 elems/thread) ----------------
__global__ __launch_bounds__(256) void cvt_kernel(const float* __restrict__ in,
                                                  bf16* __restrict__ out, int n4) {
  int i = blockIdx.x * 256 + threadIdx.x;
  if (i >= n4) return;
  float4 v = ((const float4*)in)[i];
  union { ushort4 u; bf16 h[4]; } o;
  o.h[0] = __float2bfloat16(v.x);
  o.h[1] = __float2bfloat16(v.y);
  o.h[2] = __float2bfloat16(v.z);
  o.h[3] = __float2bfloat16(v.w);
  ((ushort4*)out)[i] = o.u;
}

// ---------------- bf16 GEMM: C[M,N] = A[M,K] * Bm[N,K]^T ----------------
// 128x128 tile, BK=64, 4 waves each 64x64 (4x4 of 16x16x32 mfma).
__global__ __launch_bounds__(256) void gemm_bt(const bf16* __restrict__ A,
                                               const bf16* __restrict__ Bm,
                                               bf16* __restrict__ C,
                                               int M, int N, int K) {
  __shared__ __align__(16) bf16 As[128 * 72];  // +8 pad: 144B stride, 2-way-free
  __shared__ __align__(16) bf16 Bs[128 * 72];
  const int tid = threadIdx.x;
  const int lane = tid & 63, wave = tid >> 6;
  const int wm = (wave & 1) * 64, wn = (wave >> 1) * 64;
  const int m0 = blockIdx.x * 128, n0 = blockIdx.y * 128;
  const int quad = lane >> 4, c = lane & 15;

  f32x4 acc[4][4] = {};

  const int srow = tid >> 3;           // 0..31
  const int scol = (tid & 7) * 8;      // 0..56

  for (int kb = 0; kb < K; kb += 64) {
    __syncthreads();
#pragma unroll
    for (int i = 0; i < 4; i++) {
      int r = srow + i * 32;
      *(uint4*)(&As[r * 72 + scol]) =
          *(const uint4*)(&A[(size_t)(m0 + r) * K + kb + scol]);
      *(uint4*)(&Bs[r * 72 + scol]) =
          *(const uint4*)(&Bm[(size_t)(n0 + r) * K + kb + scol]);
    }
    __syncthreads();
#pragma unroll
    for (int kk = 0; kk < 2; kk++) {
      bf16x8 af[4], bfr[4];
      int lk = kk * 32 + quad * 8;
#pragma unroll
      for (int t = 0; t < 4; t++) {
        af[t]  = *(const bf16x8*)(&As[(wm + t * 16 + c) * 72 + lk]);
        bfr[t] = *(const bf16x8*)(&Bs[(wn + t * 16 + c) * 72 + lk]);
      }
#pragma unroll
      for (int mt = 0; mt < 4; mt++)
#pragma unroll
        for (int nt = 0; nt < 4; nt++)
          acc[mt][nt] = __builtin_amdgcn_mfma_f32_16x16x32_bf16(
              af[mt], bfr[nt], acc[mt][nt], 0, 0, 0);
    }
  }
  // epilogue: C/D layout col=lane&15, row=quad*4+reg
#pragma unroll
  for (int mt = 0; mt < 4; mt++)
#pragma unroll
    for (int nt = 0; nt < 4; nt++)
#pragma unroll
      for (int reg = 0; reg < 4; reg++) {
        int row = m0 + wm + mt * 16 + quad * 4 + reg;
        int col = n0 + wn + nt * 16 + c;
        C[(size_t)row * N + col] = __float2bfloat16(acc[mt][nt][reg]);
      }
}

// ---------------- RoPE + relayout: [B,S,nh,HD] -> [B,nh,S,HD] ----------------
// out[d]    = q[d]*cos[d]    - q[d+64]*sin[d]        (d < 64)
// out[d+64] = q[d+64]*cos[d+64] + q[d]*sin[d+64]
__global__ __launch_bounds__(256) void rope_relayout(
    const bf16* __restrict__ in, const float* __restrict__ cosp,
    const float* __restrict__ sinp, bf16* __restrict__ out, int nh, float scale) {
  int idx = blockIdx.x * 256 + threadIdx.x;  // B*S*nh*64 threads
  int d = idx & 63;
  int t = idx >> 6;
  int h = t % nh; t /= nh;
  int s = t % S_;
  int b = t / S_;
  const bf16* p = in + ((size_t)(b * S_ + s) * nh + h) * HD_;
  float q1 = __bfloat162float(p[d]);
  float q2 = __bfloat162float(p[d + 64]);
  float c1 = cosp[s * HD_ + d], c2 = cosp[s * HD_ + d + 64];
  float s1 = sinp[s * HD_ + d], s2 = sinp[s * HD_ + d + 64];
  float o1 = (q1 * c1 - q2 * s1) * scale;
  float o2 = (q2 * c2 + q1 * s2) * scale;
  bf16* q = out + ((size_t)(b * nh + h) * S_ + s) * HD_;
  q[d] = __float2bfloat16(o1);
  q[d + 64] = __float2bfloat16(o2);
}

// ---------------- V transpose: [B,S,NKV,HD] -> [B,NKV,HD,S] ----------------
__global__ __launch_bounds__(256) void v_transpose(const bf16* __restrict__ in,
                                                   bf16* __restrict__ out) {
  __shared__ __align__(16) bf16 tile[64][HD_ + 8];  // 64 x 136
  int bidx = blockIdx.x;
  int st = bidx & 31;
  int kv = (bidx >> 5) & 3;
  int b = bidx >> 7;
  int s0 = st * 64;
  int t = threadIdx.x;
  // load 64 rows x 128 cols (coalesced along hd)
  {
    int row = t >> 2;
    int colb = (t & 3) * 32;
#pragma unroll
    for (int i = 0; i < 4; i++) {
      int col = colb + i * 8;
      *(uint4*)(&tile[row][col]) =
          *(const uint4*)(&in[((size_t)(b * S_ + s0 + row) * NKV_ + kv) * HD_ + col]);
    }
  }
  __syncthreads();
  // write: rows = hd, coalesced along s
  int sl = t & 63, hb = t >> 6;  // 4 hd rows per iteration
#pragma unroll
  for (int i = 0; i < 32; i++) {
    int hd = i * 4 + hb;
    out[((size_t)(b * NKV_ + kv) * HD_ + hd) * S_ + s0 + sl] = tile[sl][hd];
  }
}

// ---------------- Flash attention (causal, online softmax) ----------------
// Q: [B,NH,S,HD] bf16 (pre-scaled by log2e/sqrt(HD)), K: [B,NKV,S,HD] bf16,
// Vt: [B,NKV,HD,S] bf16, O: [B,S,NH*HD] f32.
// Block: 256 thr = 4 waves; 64 Q rows/block (16/wave); BN=64 keys/tile.
__global__ __launch_bounds__(256) void attn_kernel(const bf16* __restrict__ Q,
                                                   const bf16* __restrict__ Kr,
                                                   const bf16* __restrict__ Vt,
                                                   float* __restrict__ O) {
  __shared__ __align__(16) bf16 Ks[64 * 136];   // 64 keys x 128 hd (+8 pad)
  __shared__ __align__(16) bf16 Vs[128 * 72];   // 128 hd x 64 keys (+8 pad)
  __shared__ __align__(16) bf16 Ps[4][16 * 72]; // per-wave P staging

  const int tid = threadIdx.x, lane = tid & 63, wave = tid >> 6;
  const int qt = blockIdx.x;              // S/64 tiles
  const int bh = blockIdx.y;
  const int b = bh >> 4, h = bh & 15, kv = h >> 2;
  const int q0 = qt * 64;
  const int quad = lane >> 4, c = lane & 15;

  // Q fragments held in registers (A-operand: m=lane&15, k=quad*8+j)
  bf16x8 qf[4];
  {
    const bf16* qp = Q + ((size_t)(b * NH_ + h) * S_ + q0 + wave * 16 + c) * HD_;
#pragma unroll
    for (int kt = 0; kt < 4; kt++)
      qf[kt] = *(const bf16x8*)(qp + kt * 32 + quad * 8);
  }

  f32x4 o_acc[8] = {};
  float m_i[4], l_i[4];
#pragma unroll
  for (int r = 0; r < 4; r++) { m_i[r] = -INFINITY; l_i[r] = 0.f; }

  const bf16* kbase = Kr + (size_t)(b * NKV_ + kv) * S_ * HD_;
  const bf16* vbase = Vt + (size_t)(b * NKV_ + kv) * HD_ * S_;

  const int ntiles = qt + 1;
  for (int it = 0; it < ntiles; it++) {
    const int kb = it * 64;
    __syncthreads();
    // stage K tile: 64 rows x 128 hd
    {
      int row = tid >> 2;
      int colb = (tid & 3) * 32;
      const bf16* kp = kbase + (size_t)(kb + row) * HD_ + colb;
#pragma unroll
      for (int i = 0; i < 4; i++)
        *(uint4*)(&Ks[row * 136 + colb + i * 8]) = *(const uint4*)(kp + i * 8);
      // stage V tile: 128 hd rows x 64 keys
      int vrow = tid >> 1;
      int vcolb = (tid & 1) * 32;
      const bf16* vp = vbase + (size_t)vrow * S_ + kb + vcolb;
#pragma unroll
      for (int i = 0; i < 4; i++)
        *(uint4*)(&Vs[vrow * 72 + vcolb + i * 8]) = *(const uint4*)(vp + i * 8);
    }
    __syncthreads();

    // scores: [16 q x 64 k] per wave
    f32x4 sacc[4] = {};
#pragma unroll
    for (int kt = 0; kt < 4; kt++) {
#pragma unroll
      for (int nt = 0; nt < 4; nt++) {
        bf16x8 kf = *(const bf16x8*)(&Ks[(nt * 16 + c) * 136 + kt * 32 + quad * 8]);
        sacc[nt] = __builtin_amdgcn_mfma_f32_16x16x32_bf16(qf[kt], kf, sacc[nt], 0, 0, 0);
      }
    }

    if (kb == q0) {  // diagonal tile: causal mask
#pragma unroll
      for (int nt = 0; nt < 4; nt++)
#pragma unroll
        for (int r = 0; r < 4; r++) {
          int col = nt * 16 + c;
          int row = wave * 16 + quad * 4 + r;
          if (col > row) sacc[nt][r] = -INFINITY;
        }
    }

    // online softmax (exp2 domain; scale folded into Q)
    float mnew[4], alpha[4];
#pragma unroll
    for (int r = 0; r < 4; r++) {
      float mx = fmaxf(fmaxf(sacc[0][r], sacc[1][r]), fmaxf(sacc[2][r], sacc[3][r]));
#pragma unroll
      for (int off = 1; off < 16; off <<= 1)
        mx = fmaxf(mx, __shfl_xor(mx, off, 64));
      mnew[r] = fmaxf(m_i[r], mx);
      alpha[r] = exp2f(m_i[r] - mnew[r]);
      m_i[r] = mnew[r];
    }

    float rowsum[4] = {0.f, 0.f, 0.f, 0.f};
#pragma unroll
    for (int nt = 0; nt < 4; nt++)
#pragma unroll
      for (int r = 0; r < 4; r++) {
        float p = exp2f(sacc[nt][r] - mnew[r]);
        rowsum[r] += p;
        Ps[wave][(quad * 4 + r) * 72 + nt * 16 + c] = __float2bfloat16(p);
      }
#pragma unroll
    for (int r = 0; r < 4; r++) {
      float s = rowsum[r];
#pragma unroll
      for (int off = 1; off < 16; off <<= 1) s += __shfl_xor(s, off, 64);
      l_i[r] = l_i[r] * alpha[r] + s;
    }
#pragma unroll
    for (int nt = 0; nt < 8; nt++)
#pragma unroll
      for (int r = 0; r < 4; r++) o_acc[nt][r] *= alpha[r];

    __syncthreads();  // guarantee P writes visible before A-frag reads

    // PV: P[16 x 64] @ V[64 x 128]
#pragma unroll
    for (int kk = 0; kk < 2; kk++) {
      bf16x8 pf = *(const bf16x8*)(&Ps[wave][c * 72 + kk * 32 + quad * 8]);
#pragma unroll
      for (int nt = 0; nt < 8; nt++) {
        bf16x8 vf = *(const bf16x8*)(&Vs[(nt * 16 + c) * 72 + kk * 32 + quad * 8]);
        o_acc[nt] = __builtin_amdgcn_mfma_f32_16x16x32_bf16(pf, vf, o_acc[nt], 0, 0, 0);
      }
    }
  }

  // epilogue: O[b, s, h*HD + hd] f32
  float inv_l[4];
#pragma unroll
  for (int r = 0; r < 4; r++) inv_l[r] = 1.f / l_i[r];
  float* obase = O + (size_t)b * S_ * D_ + (size_t)h * HD_;
  int srow0 = q0 + wave * 16 + quad * 4;
#pragma unroll
  for (int nt = 0; nt < 8; nt++)
#pragma unroll
    for (int r = 0; r < 4; r++)
      obase[(size_t)(srow0 + r) * D_ + nt * 16 + c] = o_acc[nt][r] * inv_l[r];
}

// ---------------- host launch ----------------
extern "C" void kernel_launch(void* const* d_in, const int* in_sizes, int n_in,
                              void* d_out, int out_size, void* d_ws, size_t ws_size,
                              hipStream_t stream) {
  const float* x    = (const float*)d_in[0];
  const float* cosp = (const float*)d_in[1];
  const float* sinp = (const float*)d_in[2];
  const float* wq   = (const float*)d_in[3];
  const float* wk   = (const float*)d_in[4];
  const float* wv   = (const float*)d_in[5];
  float* out = (float*)d_out;

  char* ws = (char*)d_ws;
  const size_t MB = 1024 * 1024;
  bf16* xb   = (bf16*)(ws + 0);        // 32MB; reused as qr after GEMMs
  bf16* qr   = (bf16*)(ws + 0);
  bf16* wqb  = (bf16*)(ws + 32 * MB);  // 8MB
  bf16* wkb  = (bf16*)(ws + 40 * MB);  // 2MB
  bf16* wvb  = (bf16*)(ws + 42 * MB);  // 2MB
  bf16* qlin = (bf16*)(ws + 44 * MB);  // 32MB
  bf16* klin = (bf16*)(ws + 76 * MB);  // 8MB
  bf16* vlin = (bf16*)(ws + 84 * MB);  // 8MB
  bf16* kr   = (bf16*)(ws + 92 * MB);  // 8MB
  bf16* vt   = (bf16*)(ws + 100 * MB); // 8MB

  // conversions
  cvt_kernel<<<16384, 256, 0, stream>>>(x, xb, 4194304);
  cvt_kernel<<<4096, 256, 0, stream>>>(wq, wqb, 1048576);
  cvt_kernel<<<1024, 256, 0, stream>>>(wk, wkb, 262144);
  cvt_kernel<<<1024, 256, 0, stream>>>(wv, wvb, 262144);

  // projections
  gemm_bt<<<dim3(64, 16), 256, 0, stream>>>(xb, wqb, qlin, 8192, 2048, 2048);
  gemm_bt<<<dim3(64, 4), 256, 0, stream>>>(xb, wkb, klin, 8192, 512, 2048);
  gemm_bt<<<dim3(64, 4), 256, 0, stream>>>(xb, wvb, vlin, 8192, 512, 2048);

  // rope + relayout; fold softmax scale * log2(e) into Q
  const float qscale = 1.4426950408889634f / 11.313708498984761f;
  rope_relayout<<<32768, 256, 0, stream>>>(qlin, cosp, sinp, qr, NH_, qscale);
  rope_relayout<<<8192, 256, 0, stream>>>(klin, cosp, sinp, kr, NKV_, 1.0f);
  v_transpose<<<512, 256, 0, stream>>>(vlin, vt);

  // attention
  attn_kernel<<<dim3(32, 64), 256, 0, stream>>>(qr, kr, vt, out);
}

// Round 2
// 560.753 us; speedup vs baseline: 1.1672x; 1.1672x over previous
//
#include <hip/hip_runtime.h>
#include <hip/hip_bf16.h>
#include <math.h>

#define B_ 4
#define S_ 2048
#define D_ 2048
#define NH_ 16
#define NKV_ 4
#define HD_ 128

typedef short bf16x8 __attribute__((ext_vector_type(8)));
typedef float f32x4 __attribute__((ext_vector_type(4)));
typedef __hip_bfloat16 bf16;

// async 16B/lane global->LDS: lds dest = uniform base + lane*16
#define ASYNC_CP16(gp, lp)                                                    \
  __builtin_amdgcn_global_load_lds(                                           \
      (const __attribute__((address_space(1))) unsigned int*)(gp),            \
      (__attribute__((address_space(3))) unsigned int*)(lp), 16, 0, 0)

__device__ __forceinline__ short f2b(float f) {
  union { bf16 h; short s; } u;
  u.h = __float2bfloat16(f);
  return u.s;
}

// ---------------- f32 -> bf16 conversion (4 elems/thread) ----------------
__global__ __launch_bounds__(256) void cvt_kernel(const float* __restrict__ in,
                                                  bf16* __restrict__ out, int n4) {
  int i = blockIdx.x * 256 + threadIdx.x;
  if (i >= n4) return;
  float4 v = ((const float4*)in)[i];
  union { ushort4 u; bf16 h[4]; } o;
  o.h[0] = __float2bfloat16(v.x);
  o.h[1] = __float2bfloat16(v.y);
  o.h[2] = __float2bfloat16(v.z);
  o.h[3] = __float2bfloat16(v.w);
  ((ushort4*)out)[i] = o.u;
}

// ---------------- bf16 GEMM: C[M,N] = A[M,K] * Bm[N,K]^T ----------------
// 128x128 tile, BK=64, global_load_lds staging, XOR-swizzled LDS (no pad).
// LDS slot (row, gs) holds global col-group gs ^ (row&7); readers of group g
// read slot g ^ (row&7) -> bank spread = conflict-free.
__global__ __launch_bounds__(256) void gemm_bt(const bf16* __restrict__ A,
                                               const bf16* __restrict__ Bm,
                                               bf16* __restrict__ C,
                                               int M, int N, int K) {
  __shared__ __align__(16) bf16 As[128 * 64];
  __shared__ __align__(16) bf16 Bs[128 * 64];
  const int tid = threadIdx.x;
  const int lane = tid & 63, wave = tid >> 6;
  const int wm = (wave & 1) * 64, wn = (wave >> 1) * 64;
  const int m0 = blockIdx.x * 128, n0 = blockIdx.y * 128;
  const int quad = lane >> 4, c = lane & 15;

  f32x4 acc[4][4] = {};

  // staging: wave covers rows wave*32 .. wave*32+31, 8 rows per 1KB inst
  const int sr = lane >> 3;          // row within 8-row group
  const int sg = lane & 7;           // lds slot within row
  const int gc = (sg ^ sr) * 8;      // swizzled global col group (r&7 == sr)
  const bf16* Ap = A + (size_t)(m0 + wave * 32 + sr) * K + gc;
  const bf16* Bp = Bm + (size_t)(n0 + wave * 32 + sr) * K + gc;

  for (int kb = 0; kb < K; kb += 64) {
    __syncthreads();
#pragma unroll
    for (int i = 0; i < 4; i++) {
      ASYNC_CP16(Ap + (size_t)(i * 8) * K + kb, &As[(wave * 32 + i * 8) * 64]);
      ASYNC_CP16(Bp + (size_t)(i * 8) * K + kb, &Bs[(wave * 32 + i * 8) * 64]);
    }
    __syncthreads();
#pragma unroll
    for (int kk = 0; kk < 2; kk++) {
      const int slot = ((kk * 4 + quad) ^ (c & 7)) * 8;
      bf16x8 af[4], bfr[4];
#pragma unroll
      for (int t = 0; t < 4; t++) {
        af[t]  = *(const bf16x8*)(&As[(wm + t * 16 + c) * 64 + slot]);
        bfr[t] = *(const bf16x8*)(&Bs[(wn + t * 16 + c) * 64 + slot]);
      }
#pragma unroll
      for (int mt = 0; mt < 4; mt++)
#pragma unroll
        for (int nt = 0; nt < 4; nt++)
          acc[mt][nt] = __builtin_amdgcn_mfma_f32_16x16x32_bf16(
              af[mt], bfr[nt], acc[mt][nt], 0, 0, 0);
    }
  }
#pragma unroll
  for (int mt = 0; mt < 4; mt++)
#pragma unroll
    for (int nt = 0; nt < 4; nt++)
#pragma unroll
      for (int reg = 0; reg < 4; reg++) {
        int row = m0 + wm + mt * 16 + quad * 4 + reg;
        int col = n0 + wn + nt * 16 + c;
        C[(size_t)row * N + col] = __float2bfloat16(acc[mt][nt][reg]);
      }
}

// ---------------- RoPE + relayout: qkv[B*S, stride] -> [B,nh,S,HD] ----------
__global__ __launch_bounds__(256) void rope_relayout(
    const bf16* __restrict__ in, int instride, const float* __restrict__ cosp,
    const float* __restrict__ sinp, bf16* __restrict__ out, int nh, float scale) {
  int idx = blockIdx.x * 256 + threadIdx.x;
  int d = idx & 63;
  int t = idx >> 6;
  int h = t % nh; t /= nh;
  int s = t % S_;
  int b = t / S_;
  const bf16* p = in + (size_t)(b * S_ + s) * instride + h * HD_;
  float q1 = __bfloat162float(p[d]);
  float q2 = __bfloat162float(p[d + 64]);
  float c1 = cosp[s * HD_ + d], c2 = cosp[s * HD_ + d + 64];
  float s1 = sinp[s * HD_ + d], s2 = sinp[s * HD_ + d + 64];
  float o1 = (q1 * c1 - q2 * s1) * scale;
  float o2 = (q2 * c2 + q1 * s2) * scale;
  bf16* q = out + ((size_t)(b * nh + h) * S_ + s) * HD_;
  q[d] = __float2bfloat16(o1);
  q[d + 64] = __float2bfloat16(o2);
}

// ---------------- V transpose: qkv[B*S, stride] v-block -> [B,NKV,HD,S] -----
__global__ __launch_bounds__(256) void v_transpose(const bf16* __restrict__ in,
                                                   int instride,
                                                   bf16* __restrict__ out) {
  __shared__ __align__(16) bf16 tile[64][HD_ + 8];
  int bidx = blockIdx.x;
  int st = bidx & 31;
  int kv = (bidx >> 5) & 3;
  int b = bidx >> 7;
  int s0 = st * 64;
  int t = threadIdx.x;
  {
    int row = t >> 2;
    int colb = (t & 3) * 32;
#pragma unroll
    for (int i = 0; i < 4; i++) {
      int col = colb + i * 8;
      *(uint4*)(&tile[row][col]) = *(const uint4*)(
          &in[(size_t)(b * S_ + s0 + row) * instride + kv * HD_ + col]);
    }
  }
  __syncthreads();
  int sl = t & 63, hb = t >> 6;
#pragma unroll
  for (int i = 0; i < 32; i++) {
    int hd = i * 4 + hb;
    out[((size_t)(b * NKV_ + kv) * HD_ + hd) * S_ + s0 + sl] = tile[sl][hd];
  }
}

// ---------------- Flash attention, paired causal tiles ----------------
// S^T = K*Q^T so each lane owns ONE q (q = lane&15): in-lane softmax.
// Ks[64 key x 128 hd], Vs[128 hd x 64 key], both XOR-swizzled, staged via
// global_load_lds. Ps per-wave [16 q x 64 key] stride 72 (padded).
__device__ __forceinline__ void attn_step(
    const bf16* __restrict__ Ks, const bf16* __restrict__ Vs,
    bf16* __restrict__ Psw, const bf16x8* qf, f32x4* o,
    float& m_i, float& l_i, bool diag, int kb, int qbase, int quad, int c) {
  f32x4 sacc[4] = {};
#pragma unroll
  for (int kt = 0; kt < 4; kt++) {
    const int slot = ((kt * 4 + quad) ^ (c & 7)) * 8;
#pragma unroll
    for (int mt = 0; mt < 4; mt++) {
      bf16x8 kf = *(const bf16x8*)(&Ks[(mt * 16 + c) * 128 + slot]);
      sacc[mt] = __builtin_amdgcn_mfma_f32_16x16x32_bf16(kf, qf[kt], sacc[mt], 0, 0, 0);
    }
  }
  if (diag) {
    const int qg = qbase + c;
#pragma unroll
    for (int mt = 0; mt < 4; mt++)
#pragma unroll
      for (int r = 0; r < 4; r++)
        if (kb + mt * 16 + quad * 4 + r > qg) sacc[mt][r] = -INFINITY;
  }
  float mx = sacc[0][0];
#pragma unroll
  for (int mt = 0; mt < 4; mt++)
#pragma unroll
    for (int r = 0; r < 4; r++) mx = fmaxf(mx, sacc[mt][r]);
  mx = fmaxf(mx, __shfl_xor(mx, 16, 64));
  mx = fmaxf(mx, __shfl_xor(mx, 32, 64));
  const float mnew = fmaxf(m_i, mx);
  const float alpha = exp2f(m_i - mnew);
  m_i = mnew;
  float rs = 0.f;
#pragma unroll
  for (int mt = 0; mt < 4; mt++) {
    short4 pk;
    float p0 = exp2f(sacc[mt][0] - mnew);
    float p1 = exp2f(sacc[mt][1] - mnew);
    float p2 = exp2f(sacc[mt][2] - mnew);
    float p3 = exp2f(sacc[mt][3] - mnew);
    rs += (p0 + p1) + (p2 + p3);
    pk.x = f2b(p0); pk.y = f2b(p1); pk.z = f2b(p2); pk.w = f2b(p3);
    *(short4*)(&Psw[c * 72 + mt * 16 + quad * 4]) = pk;
  }
  rs += __shfl_xor(rs, 16, 64);
  rs += __shfl_xor(rs, 32, 64);
  l_i = l_i * alpha + rs;
  if (__any(alpha != 1.0f)) {
    float a0 = __shfl(alpha, quad * 4 + 0, 64);
    float a1 = __shfl(alpha, quad * 4 + 1, 64);
    float a2 = __shfl(alpha, quad * 4 + 2, 64);
    float a3 = __shfl(alpha, quad * 4 + 3, 64);
#pragma unroll
    for (int nt = 0; nt < 8; nt++) {
      o[nt][0] *= a0; o[nt][1] *= a1; o[nt][2] *= a2; o[nt][3] *= a3;
    }
  }
#pragma unroll
  for (int kk = 0; kk < 2; kk++) {
    bf16x8 pf = *(const bf16x8*)(&Psw[c * 72 + kk * 32 + quad * 8]);
    const int slot = ((kk * 4 + quad) ^ (c & 7)) * 8;
#pragma unroll
    for (int nt = 0; nt < 8; nt++) {
      bf16x8 vf = *(const bf16x8*)(&Vs[(nt * 16 + c) * 64 + slot]);
      o[nt] = __builtin_amdgcn_mfma_f32_16x16x32_bf16(pf, vf, o[nt], 0, 0, 0);
    }
  }
}

__device__ __forceinline__ void attn_epilogue(const f32x4* o, float l_i,
                                              float* __restrict__ O, int b, int h,
                                              int row0, int quad, int c) {
  float inv[4];
#pragma unroll
  for (int r = 0; r < 4; r++) inv[r] = 1.0f / __shfl(l_i, quad * 4 + r, 64);
  float* obase = O + (size_t)b * S_ * D_ + (size_t)h * HD_;
#pragma unroll
  for (int nt = 0; nt < 8; nt++)
#pragma unroll
    for (int r = 0; r < 4; r++)
      obase[(size_t)(row0 + quad * 4 + r) * D_ + nt * 16 + c] = o[nt][r] * inv[r];
}

__global__ __launch_bounds__(256, 2) void attn_kernel(const bf16* __restrict__ Q,
                                                      const bf16* __restrict__ Kr,
                                                      const bf16* __restrict__ Vt,
                                                      float* __restrict__ O) {
  __shared__ __align__(16) bf16 Ks[64 * 128];
  __shared__ __align__(16) bf16 Vs[128 * 64];
  __shared__ __align__(16) bf16 Ps[4][16 * 72];

  const int tid = threadIdx.x, lane = tid & 63, wave = tid >> 6;
  const int quad = lane >> 4, c = lane & 15;
  const int j = blockIdx.x;                 // pair index 0..15
  const int bh = blockIdx.y;
  const int b = bh >> 4, h = bh & 15, kv = h >> 2;
  const int tlo = j, thi = 31 - j;
  const int q0lo = tlo * 64, q0hi = thi * 64;
  bf16* Psw = &Ps[wave][0];

  // Q fragments (A-layout == B-layout for transposed use): lane holds q=c
  bf16x8 qlo[4], qhi[4];
  {
    const bf16* ql = Q + ((size_t)(b * NH_ + h) * S_ + q0lo + wave * 16 + c) * HD_;
    const bf16* qh = Q + ((size_t)(b * NH_ + h) * S_ + q0hi + wave * 16 + c) * HD_;
#pragma unroll
    for (int kt = 0; kt < 4; kt++) {
      qlo[kt] = *(const bf16x8*)(ql + kt * 32 + quad * 8);
      qhi[kt] = *(const bf16x8*)(qh + kt * 32 + quad * 8);
    }
  }

  f32x4 o_lo[8] = {}, o_hi[8] = {};
  float m_lo = -INFINITY, l_lo = 0.f, m_hi = -INFINITY, l_hi = 0.f;

  const bf16* kbase = Kr + (size_t)(b * NKV_ + kv) * S_ * HD_;
  const bf16* vbase = Vt + (size_t)(b * NKV_ + kv) * HD_ * S_;

  // staging offsets (elements)
  int koff[4], voff;
  {
    const int kl = lane >> 4;       // row-in-group for K (4 rows/inst)
    const int ks = lane & 15;
#pragma unroll
    for (int i = 0; i < 4; i++) {
      int r = wave * 16 + i * 4 + kl;
      koff[i] = r * HD_ + ((ks ^ (r & 7)) * 8);
    }
    const int vl = lane >> 3;       // row-in-group for V (8 rows/inst)
    const int vs = lane & 7;
    voff = (wave * 32 + vl) * S_ + ((vs ^ (vl & 7)) * 8);
  }

  const int qbl = q0lo + wave * 16, qbh = q0hi + wave * 16;

  for (int it = 0; it <= thi; ++it) {
    const int kb = it * 64;
    __syncthreads();
#pragma unroll
    for (int i = 0; i < 4; i++) {
      ASYNC_CP16(kbase + (size_t)kb * HD_ + koff[i], &Ks[(wave * 16 + i * 4) * 128]);
      ASYNC_CP16(vbase + kb + voff + (size_t)(i * 8) * S_, &Vs[(wave * 32 + i * 8) * 64]);
    }
    __syncthreads();
    attn_step(Ks, Vs, Psw, qhi, o_hi, m_hi, l_hi, it == thi, kb, qbh, quad, c);
    if (it <= tlo)
      attn_step(Ks, Vs, Psw, qlo, o_lo, m_lo, l_lo, it == tlo, kb, qbl, quad, c);
  }

  attn_epilogue(o_hi, l_hi, O, b, h, qbh, quad, c);
  attn_epilogue(o_lo, l_lo, O, b, h, qbl, quad, c);
}

// ---------------- host launch ----------------
extern "C" void kernel_launch(void* const* d_in, const int* in_sizes, int n_in,
                              void* d_out, int out_size, void* d_ws, size_t ws_size,
                              hipStream_t stream) {
  const float* x    = (const float*)d_in[0];
  const float* cosp = (const float*)d_in[1];
  const float* sinp = (const float*)d_in[2];
  const float* wq   = (const float*)d_in[3];
  const float* wk   = (const float*)d_in[4];
  const float* wv   = (const float*)d_in[5];
  float* out = (float*)d_out;

  char* ws = (char*)d_ws;
  const size_t MB = 1024 * 1024;
  bf16* xb    = (bf16*)(ws + 0);         // 32MB (dead after gemm)
  bf16* qr    = (bf16*)(ws + 0);         // reuse
  bf16* wqkvb = (bf16*)(ws + 32 * MB);   // 12MB: [3072, 2048] concat
  bf16* qkv   = (bf16*)(ws + 44 * MB);   // 48MB: [8192, 3072]
  bf16* kr    = (bf16*)(ws + 92 * MB);   // 8MB
  bf16* vt    = (bf16*)(ws + 100 * MB);  // 8MB

  cvt_kernel<<<16384, 256, 0, stream>>>(x, xb, 4194304);
  cvt_kernel<<<4096, 256, 0, stream>>>(wq, wqkvb, 1048576);
  cvt_kernel<<<1024, 256, 0, stream>>>(wk, wqkvb + 4194304, 262144);
  cvt_kernel<<<1024, 256, 0, stream>>>(wv, wqkvb + 5242880, 262144);

  gemm_bt<<<dim3(64, 24), 256, 0, stream>>>(xb, wqkvb, qkv, 8192, 3072, 2048);

  const float qscale = 1.4426950408889634f / 11.313708498984761f;
  rope_relayout<<<32768, 256, 0, stream>>>(qkv, 3072, cosp, sinp, qr, NH_, qscale);
  rope_relayout<<<8192, 256, 0, stream>>>(qkv + 2048, 3072, cosp, sinp, kr, NKV_, 1.0f);
  v_transpose<<<512, 256, 0, stream>>>(qkv + 2560, 3072, vt);

  attn_kernel<<<dim3(16, 64), 256, 0, stream>>>(qr, kr, vt, out);
}

// Round 3
// 434.330 us; speedup vs baseline: 1.5069x; 1.2911x over previous
//
#include <hip/hip_runtime.h>
#include <hip/hip_bf16.h>
#include <math.h>

#define B_ 4
#define S_ 2048
#define D_ 2048
#define NH_ 16
#define NKV_ 4
#define HD_ 128

typedef short bf16x8 __attribute__((ext_vector_type(8)));
typedef float f32x4 __attribute__((ext_vector_type(4)));
typedef __hip_bfloat16 bf16;

// async 16B/lane global->LDS: lds dest = uniform base + lane*16
#define ASYNC_CP16(gp, lp)                                                    \
  __builtin_amdgcn_global_load_lds(                                           \
      (const __attribute__((address_space(1))) unsigned int*)(gp),            \
      (__attribute__((address_space(3))) unsigned int*)(lp), 16, 0, 0)

__device__ __forceinline__ short f2b(float f) {
  union { bf16 h; short s; } u;
  u.h = __float2bfloat16(f);
  return u.s;
}

// ---------------- f32 -> bf16 conversion (4 elems/thread) ----------------
__global__ __launch_bounds__(256) void cvt_kernel(const float* __restrict__ in,
                                                  bf16* __restrict__ out, int n4) {
  int i = blockIdx.x * 256 + threadIdx.x;
  if (i >= n4) return;
  float4 v = ((const float4*)in)[i];
  union { ushort4 u; bf16 h[4]; } o;
  o.h[0] = __float2bfloat16(v.x);
  o.h[1] = __float2bfloat16(v.y);
  o.h[2] = __float2bfloat16(v.z);
  o.h[3] = __float2bfloat16(v.w);
  ((ushort4*)out)[i] = o.u;
}

// ---------------- bf16 GEMM: C[M,N] = A[M,K] * Bm[N,K]^T ----------------
// 128x128 tile, BK=64, global_load_lds staging, XOR-swizzled LDS (no pad).
__global__ __launch_bounds__(256) void gemm_bt(const bf16* __restrict__ A,
                                               const bf16* __restrict__ Bm,
                                               bf16* __restrict__ C,
                                               int M, int N, int K) {
  __shared__ __align__(16) bf16 As[128 * 64];
  __shared__ __align__(16) bf16 Bs[128 * 64];
  const int tid = threadIdx.x;
  const int lane = tid & 63, wave = tid >> 6;
  const int wm = (wave & 1) * 64, wn = (wave >> 1) * 64;
  const int m0 = blockIdx.x * 128, n0 = blockIdx.y * 128;
  const int quad = lane >> 4, c = lane & 15;

  f32x4 acc[4][4] = {};

  const int sr = lane >> 3;          // row within 8-row group
  const int sg = lane & 7;           // lds slot within row
  const int gc = (sg ^ sr) * 8;      // swizzled global col group
  const bf16* Ap = A + (size_t)(m0 + wave * 32 + sr) * K + gc;
  const bf16* Bp = Bm + (size_t)(n0 + wave * 32 + sr) * K + gc;

  for (int kb = 0; kb < K; kb += 64) {
    __syncthreads();
#pragma unroll
    for (int i = 0; i < 4; i++) {
      ASYNC_CP16(Ap + (size_t)(i * 8) * K + kb, &As[(wave * 32 + i * 8) * 64]);
      ASYNC_CP16(Bp + (size_t)(i * 8) * K + kb, &Bs[(wave * 32 + i * 8) * 64]);
    }
    __syncthreads();
#pragma unroll
    for (int kk = 0; kk < 2; kk++) {
      const int slot = ((kk * 4 + quad) ^ (c & 7)) * 8;
      bf16x8 af[4], bfr[4];
#pragma unroll
      for (int t = 0; t < 4; t++) {
        af[t]  = *(const bf16x8*)(&As[(wm + t * 16 + c) * 64 + slot]);
        bfr[t] = *(const bf16x8*)(&Bs[(wn + t * 16 + c) * 64 + slot]);
      }
#pragma unroll
      for (int mt = 0; mt < 4; mt++)
#pragma unroll
        for (int nt = 0; nt < 4; nt++)
          acc[mt][nt] = __builtin_amdgcn_mfma_f32_16x16x32_bf16(
              af[mt], bfr[nt], acc[mt][nt], 0, 0, 0);
    }
  }
#pragma unroll
  for (int mt = 0; mt < 4; mt++)
#pragma unroll
    for (int nt = 0; nt < 4; nt++)
#pragma unroll
      for (int reg = 0; reg < 4; reg++) {
        int row = m0 + wm + mt * 16 + quad * 4 + reg;
        int col = n0 + wn + nt * 16 + c;
        C[(size_t)row * N + col] = __float2bfloat16(acc[mt][nt][reg]);
      }
}

// ---------------- RoPE + relayout: qkv[B*S, stride] -> [B,nh,S,HD] ----------
__global__ __launch_bounds__(256) void rope_relayout(
    const bf16* __restrict__ in, int instride, const float* __restrict__ cosp,
    const float* __restrict__ sinp, bf16* __restrict__ out, int nh, float scale) {
  int idx = blockIdx.x * 256 + threadIdx.x;
  int d = idx & 63;
  int t = idx >> 6;
  int h = t % nh; t /= nh;
  int s = t % S_;
  int b = t / S_;
  const bf16* p = in + (size_t)(b * S_ + s) * instride + h * HD_;
  float q1 = __bfloat162float(p[d]);
  float q2 = __bfloat162float(p[d + 64]);
  float c1 = cosp[s * HD_ + d], c2 = cosp[s * HD_ + d + 64];
  float s1 = sinp[s * HD_ + d], s2 = sinp[s * HD_ + d + 64];
  float o1 = (q1 * c1 - q2 * s1) * scale;
  float o2 = (q2 * c2 + q1 * s2) * scale;
  bf16* q = out + ((size_t)(b * nh + h) * S_ + s) * HD_;
  q[d] = __float2bfloat16(o1);
  q[d + 64] = __float2bfloat16(o2);
}

// ---------------- V transpose: qkv[B*S, stride] v-block -> [B,NKV,HD,S] -----
__global__ __launch_bounds__(256) void v_transpose(const bf16* __restrict__ in,
                                                   int instride,
                                                   bf16* __restrict__ out) {
  __shared__ __align__(16) bf16 tile[64][HD_ + 8];
  int bidx = blockIdx.x;
  int st = bidx & 31;
  int kv = (bidx >> 5) & 3;
  int b = bidx >> 7;
  int s0 = st * 64;
  int t = threadIdx.x;
  {
    int row = t >> 2;
    int colb = (t & 3) * 32;
#pragma unroll
    for (int i = 0; i < 4; i++) {
      int col = colb + i * 8;
      *(uint4*)(&tile[row][col]) = *(const uint4*)(
          &in[(size_t)(b * S_ + s0 + row) * instride + kv * HD_ + col]);
    }
  }
  __syncthreads();
  int sl = t & 63, hb = t >> 6;
#pragma unroll
  for (int i = 0; i < 32; i++) {
    int hd = i * 4 + hb;
    out[((size_t)(b * NKV_ + kv) * HD_ + hd) * S_ + s0 + sl] = tile[sl][hd];
  }
}

// ---------------- Flash attention, paired causal tiles (sequential) --------
// S^T = K*Q^T so each lane owns ONE q (q = lane&15): in-lane softmax.
__device__ __forceinline__ void attn_step(
    const bf16* __restrict__ Ks, const bf16* __restrict__ Vs,
    bf16* __restrict__ Psw, const bf16x8* qf, f32x4* o,
    float& m_i, float& l_i, bool diag, int kb, int qbase, int quad, int c) {
  f32x4 sacc[4] = {};
#pragma unroll
  for (int kt = 0; kt < 4; kt++) {
    const int slot = ((kt * 4 + quad) ^ (c & 7)) * 8;
#pragma unroll
    for (int mt = 0; mt < 4; mt++) {
      bf16x8 kf = *(const bf16x8*)(&Ks[(mt * 16 + c) * 128 + slot]);
      sacc[mt] = __builtin_amdgcn_mfma_f32_16x16x32_bf16(kf, qf[kt], sacc[mt], 0, 0, 0);
    }
  }
  if (diag) {
    const int qg = qbase + c;
#pragma unroll
    for (int mt = 0; mt < 4; mt++)
#pragma unroll
      for (int r = 0; r < 4; r++)
        if (kb + mt * 16 + quad * 4 + r > qg) sacc[mt][r] = -INFINITY;
  }
  float mx = sacc[0][0];
#pragma unroll
  for (int mt = 0; mt < 4; mt++)
#pragma unroll
    for (int r = 0; r < 4; r++) mx = fmaxf(mx, sacc[mt][r]);
  mx = fmaxf(mx, __shfl_xor(mx, 16, 64));
  mx = fmaxf(mx, __shfl_xor(mx, 32, 64));
  const float mnew = fmaxf(m_i, mx);
  const float alpha = exp2f(m_i - mnew);
  m_i = mnew;
  float rs = 0.f;
#pragma unroll
  for (int mt = 0; mt < 4; mt++) {
    short4 pk;
    float p0 = exp2f(sacc[mt][0] - mnew);
    float p1 = exp2f(sacc[mt][1] - mnew);
    float p2 = exp2f(sacc[mt][2] - mnew);
    float p3 = exp2f(sacc[mt][3] - mnew);
    rs += (p0 + p1) + (p2 + p3);
    pk.x = f2b(p0); pk.y = f2b(p1); pk.z = f2b(p2); pk.w = f2b(p3);
    *(short4*)(&Psw[c * 72 + mt * 16 + quad * 4]) = pk;
  }
  rs += __shfl_xor(rs, 16, 64);
  rs += __shfl_xor(rs, 32, 64);
  l_i = l_i * alpha + rs;
  if (__any(alpha != 1.0f)) {
    float a0 = __shfl(alpha, quad * 4 + 0, 64);
    float a1 = __shfl(alpha, quad * 4 + 1, 64);
    float a2 = __shfl(alpha, quad * 4 + 2, 64);
    float a3 = __shfl(alpha, quad * 4 + 3, 64);
#pragma unroll
    for (int nt = 0; nt < 8; nt++) {
      o[nt][0] *= a0; o[nt][1] *= a1; o[nt][2] *= a2; o[nt][3] *= a3;
    }
  }
#pragma unroll
  for (int kk = 0; kk < 2; kk++) {
    bf16x8 pf = *(const bf16x8*)(&Psw[c * 72 + kk * 32 + quad * 8]);
    const int slot = ((kk * 4 + quad) ^ (c & 7)) * 8;
#pragma unroll
    for (int nt = 0; nt < 8; nt++) {
      bf16x8 vf = *(const bf16x8*)(&Vs[(nt * 16 + c) * 64 + slot]);
      o[nt] = __builtin_amdgcn_mfma_f32_16x16x32_bf16(pf, vf, o[nt], 0, 0, 0);
    }
  }
}

__global__ __launch_bounds__(256) void attn_kernel(const bf16* __restrict__ Q,
                                                   const bf16* __restrict__ Kr,
                                                   const bf16* __restrict__ Vt,
                                                   float* __restrict__ O) {
  __shared__ __align__(16) bf16 Ks[64 * 128];
  __shared__ __align__(16) bf16 Vs[128 * 64];
  __shared__ __align__(16) bf16 Ps[4][16 * 72];

  const int tid = threadIdx.x, lane = tid & 63, wave = tid >> 6;
  const int quad = lane >> 4, c = lane & 15;
  const int j = blockIdx.x;                 // pair index 0..15
  const int bh = blockIdx.y;
  const int b = bh >> 4, h = bh & 15, kv = h >> 2;
  bf16* Psw = &Ps[wave][0];

  const bf16* kbase = Kr + (size_t)(b * NKV_ + kv) * S_ * HD_;
  const bf16* vbase = Vt + (size_t)(b * NKV_ + kv) * HD_ * S_;

  // staging offsets (elements)
  int koff[4], voff;
  {
    const int kl = lane >> 4;       // row-in-group for K (4 rows/inst)
    const int ks = lane & 15;
#pragma unroll
    for (int i = 0; i < 4; i++) {
      int r = wave * 16 + i * 4 + kl;
      koff[i] = r * HD_ + ((ks ^ (r & 7)) * 8);
    }
    const int vl = lane >> 3;       // row-in-group for V (8 rows/inst)
    const int vs = lane & 7;
    voff = (wave * 32 + vl) * S_ + ((vs ^ (vl & 7)) * 8);
  }

  // two sequential passes: tile j (pass 0), tile 31-j (pass 1).
  // uniform total work per block: (j+1) + (32-j) = 33 tile-steps.
#pragma unroll 1
  for (int pass = 0; pass < 2; ++pass) {
    const int qt = pass ? (31 - j) : j;
    const int q0 = qt * 64;
    const int qb = q0 + wave * 16;

    bf16x8 qf[4];
    {
      const bf16* qp = Q + ((size_t)(b * NH_ + h) * S_ + qb + c) * HD_;
#pragma unroll
      for (int kt = 0; kt < 4; kt++)
        qf[kt] = *(const bf16x8*)(qp + kt * 32 + quad * 8);
    }
    f32x4 o_acc[8] = {};
    float m_i = -INFINITY, l_i = 0.f;

#pragma unroll 1
    for (int it = 0; it <= qt; ++it) {
      const int kb = it * 64;
      __syncthreads();
#pragma unroll
      for (int i = 0; i < 4; i++) {
        ASYNC_CP16(kbase + (size_t)kb * HD_ + koff[i], &Ks[(wave * 16 + i * 4) * 128]);
        ASYNC_CP16(vbase + kb + voff + (size_t)(i * 8) * S_, &Vs[(wave * 32 + i * 8) * 64]);
      }
      __syncthreads();
      attn_step(Ks, Vs, Psw, qf, o_acc, m_i, l_i, it == qt, kb, qb, quad, c);
    }

    // epilogue
    float inv[4];
#pragma unroll
    for (int r = 0; r < 4; r++) inv[r] = 1.0f / __shfl(l_i, quad * 4 + r, 64);
    float* obase = O + (size_t)b * S_ * D_ + (size_t)h * HD_;
#pragma unroll
    for (int nt = 0; nt < 8; nt++)
#pragma unroll
      for (int r = 0; r < 4; r++)
        obase[(size_t)(qb + quad * 4 + r) * D_ + nt * 16 + c] = o_acc[nt][r] * inv[r];
  }
}

// ---------------- host launch ----------------
extern "C" void kernel_launch(void* const* d_in, const int* in_sizes, int n_in,
                              void* d_out, int out_size, void* d_ws, size_t ws_size,
                              hipStream_t stream) {
  const float* x    = (const float*)d_in[0];
  const float* cosp = (const float*)d_in[1];
  const float* sinp = (const float*)d_in[2];
  const float* wq   = (const float*)d_in[3];
  const float* wk   = (const float*)d_in[4];
  const float* wv   = (const float*)d_in[5];
  float* out = (float*)d_out;

  char* ws = (char*)d_ws;
  const size_t MB = 1024 * 1024;
  bf16* xb    = (bf16*)(ws + 0);         // 32MB (dead after gemm)
  bf16* qr    = (bf16*)(ws + 0);         // reuse
  bf16* wqkvb = (bf16*)(ws + 32 * MB);   // 12MB: [3072, 2048] concat
  bf16* qkv   = (bf16*)(ws + 44 * MB);   // 48MB: [8192, 3072]
  bf16* kr    = (bf16*)(ws + 92 * MB);   // 8MB
  bf16* vt    = (bf16*)(ws + 100 * MB);  // 8MB

  cvt_kernel<<<16384, 256, 0, stream>>>(x, xb, 4194304);
  cvt_kernel<<<4096, 256, 0, stream>>>(wq, wqkvb, 1048576);
  cvt_kernel<<<1024, 256, 0, stream>>>(wk, wqkvb + 4194304, 262144);
  cvt_kernel<<<1024, 256, 0, stream>>>(wv, wqkvb + 5242880, 262144);

  gemm_bt<<<dim3(64, 24), 256, 0, stream>>>(xb, wqkvb, qkv, 8192, 3072, 2048);

  const float qscale = 1.4426950408889634f / 11.313708498984761f;
  rope_relayout<<<32768, 256, 0, stream>>>(qkv, 3072, cosp, sinp, qr, NH_, qscale);
  rope_relayout<<<8192, 256, 0, stream>>>(qkv + 2048, 3072, cosp, sinp, kr, NKV_, 1.0f);
  v_transpose<<<512, 256, 0, stream>>>(qkv + 2560, 3072, vt);

  attn_kernel<<<dim3(16, 64), 256, 0, stream>>>(qr, kr, vt, out);
}

// Round 4
// 426.243 us; speedup vs baseline: 1.5355x; 1.0190x over previous
//
#include <hip/hip_runtime.h>
#include <hip/hip_bf16.h>
#include <math.h>

#define B_ 4
#define S_ 2048
#define D_ 2048
#define NH_ 16
#define NKV_ 4
#define HD_ 128

typedef short bf16x8 __attribute__((ext_vector_type(8)));
typedef float f32x4 __attribute__((ext_vector_type(4)));
typedef __hip_bfloat16 bf16;

// async 16B/lane global->LDS: lds dest = uniform base + lane*16
#define ASYNC_CP16(gp, lp)                                                    \
  __builtin_amdgcn_global_load_lds(                                           \
      (const __attribute__((address_space(1))) unsigned int*)(gp),            \
      (__attribute__((address_space(3))) unsigned int*)(lp), 16, 0, 0)

// ---------------- f32 -> bf16 conversion (4 elems/thread) ----------------
__global__ __launch_bounds__(256) void cvt_kernel(const float* __restrict__ in,
                                                  bf16* __restrict__ out, int n4) {
  int i = blockIdx.x * 256 + threadIdx.x;
  if (i >= n4) return;
  float4 v = ((const float4*)in)[i];
  union { ushort4 u; bf16 h[4]; } o;
  o.h[0] = __float2bfloat16(v.x);
  o.h[1] = __float2bfloat16(v.y);
  o.h[2] = __float2bfloat16(v.z);
  o.h[3] = __float2bfloat16(v.w);
  ((ushort4*)out)[i] = o.u;
}

// ---------------- fused QKV GEMM + RoPE epilogue ----------------
// C[8192, 3072] = x[8192,2048] @ W[3072,2048]^T, 128x128 tile, BK=64.
// Wave owns 32 rows x 128 cols so the RoPE pair (d, d+64) = (nt, nt+4) is
// in-lane. N-tile == one head: hblk 0..15 -> Q (rope, scaled), 16..19 -> K
// (rope), 20..23 -> V (plain write to vlin).
__global__ __launch_bounds__(256) void gemm_qkv(
    const bf16* __restrict__ A, const bf16* __restrict__ W,
    bf16* __restrict__ qr, bf16* __restrict__ kr, bf16* __restrict__ vlin,
    const float* __restrict__ cosp, const float* __restrict__ sinp,
    float qscale) {
  __shared__ __align__(16) bf16 As[128 * 64];
  __shared__ __align__(16) bf16 Bs[128 * 64];
  const int tid = threadIdx.x;
  const int lane = tid & 63, wave = tid >> 6;
  const int m0 = blockIdx.x * 128;
  const int hblk = blockIdx.y;
  const int n0 = hblk * 128;
  const int quad = lane >> 4, c = lane & 15;
  const int K = 2048;

  f32x4 acc[2][8] = {};

  const int sr = lane >> 3;          // row within 8-row group
  const int sg = lane & 7;           // lds slot within row
  const int gc = (sg ^ sr) * 8;      // swizzled global col group
  const bf16* Ap = A + (size_t)(m0 + wave * 32 + sr) * K + gc;
  const bf16* Bp = W + (size_t)(n0 + wave * 32 + sr) * K + gc;

  for (int kb = 0; kb < K; kb += 64) {
    __syncthreads();
#pragma unroll
    for (int i = 0; i < 4; i++) {
      ASYNC_CP16(Ap + (size_t)(i * 8) * K + kb, &As[(wave * 32 + i * 8) * 64]);
      ASYNC_CP16(Bp + (size_t)(i * 8) * K + kb, &Bs[(wave * 32 + i * 8) * 64]);
    }
    __syncthreads();
#pragma unroll
    for (int kk = 0; kk < 2; kk++) {
      const int slot = ((kk * 4 + quad) ^ (c & 7)) * 8;
      bf16x8 af[2], bfr[8];
#pragma unroll
      for (int t = 0; t < 2; t++)
        af[t] = *(const bf16x8*)(&As[(wave * 32 + t * 16 + c) * 64 + slot]);
#pragma unroll
      for (int t = 0; t < 8; t++)
        bfr[t] = *(const bf16x8*)(&Bs[(t * 16 + c) * 64 + slot]);
#pragma unroll
      for (int mt = 0; mt < 2; mt++)
#pragma unroll
        for (int nt = 0; nt < 8; nt++)
          acc[mt][nt] = __builtin_amdgcn_mfma_f32_16x16x32_bf16(
              af[mt], bfr[nt], acc[mt][nt], 0, 0, 0);
    }
  }

  if (hblk < 20) {
    // RoPE + direct relayout to [B, nh, S, HD]
    const float scale = (hblk < 16) ? qscale : 1.0f;
#pragma unroll
    for (int mt = 0; mt < 2; mt++)
#pragma unroll
      for (int reg = 0; reg < 4; reg++) {
        int m = m0 + wave * 32 + mt * 16 + quad * 4 + reg;
        int b = m >> 11, s = m & 2047;
        const float* cr = cosp + s * HD_;
        const float* sn = sinp + s * HD_;
        bf16* orow = (hblk < 16)
            ? qr + ((size_t)(b * NH_ + hblk) * S_ + s) * HD_
            : kr + ((size_t)(b * NKV_ + (hblk - 16)) * S_ + s) * HD_;
#pragma unroll
        for (int nt = 0; nt < 4; nt++) {
          int d1 = nt * 16 + c, d2 = d1 + 64;
          float q1 = acc[mt][nt][reg], q2 = acc[mt][nt + 4][reg];
          float o1 = (q1 * cr[d1] - q2 * sn[d1]) * scale;
          float o2 = (q2 * cr[d2] + q1 * sn[d2]) * scale;
          orow[d1] = __float2bfloat16(o1);
          orow[d2] = __float2bfloat16(o2);
        }
      }
  } else {
    // V: plain write to vlin[8192, 512]
    bf16* vbase = vlin + (size_t)(hblk - 20) * HD_;
#pragma unroll
    for (int mt = 0; mt < 2; mt++)
#pragma unroll
      for (int reg = 0; reg < 4; reg++) {
        int m = m0 + wave * 32 + mt * 16 + quad * 4 + reg;
        bf16* row = vbase + (size_t)m * (NKV_ * HD_);
#pragma unroll
        for (int nt = 0; nt < 8; nt++)
          row[nt * 16 + c] = __float2bfloat16(acc[mt][nt][reg]);
      }
  }
}

// ---------------- V transpose: vlin[B*S, 512] -> [B,NKV,HD,S] -----
__global__ __launch_bounds__(256) void v_transpose(const bf16* __restrict__ in,
                                                   int instride,
                                                   bf16* __restrict__ out) {
  __shared__ __align__(16) bf16 tile[64][HD_ + 8];
  int bidx = blockIdx.x;
  int st = bidx & 31;
  int kv = (bidx >> 5) & 3;
  int b = bidx >> 7;
  int s0 = st * 64;
  int t = threadIdx.x;
  {
    int row = t >> 2;
    int colb = (t & 3) * 32;
#pragma unroll
    for (int i = 0; i < 4; i++) {
      int col = colb + i * 8;
      *(uint4*)(&tile[row][col]) = *(const uint4*)(
          &in[(size_t)(b * S_ + s0 + row) * instride + kv * HD_ + col]);
    }
  }
  __syncthreads();
  int sl = t & 63, hb = t >> 6;
#pragma unroll
  for (int i = 0; i < 32; i++) {
    int hd = i * 4 + hb;
    out[((size_t)(b * NKV_ + kv) * HD_ + hd) * S_ + s0 + sl] = tile[sl][hd];
  }
}

// ---------------- Flash attention, paired causal tiles (sequential) --------
// S^T = K*Q^T so each lane owns ONE q (q = lane&15): in-lane softmax.
__device__ __forceinline__ void attn_step(
    const bf16* __restrict__ Ks, const bf16* __restrict__ Vs,
    bf16* __restrict__ Psw, const bf16x8* qf, f32x4* o,
    float& m_i, float& l_i, bool diag, int kb, int qbase, int quad, int c) {
  f32x4 sacc[4] = {};
#pragma unroll
  for (int kt = 0; kt < 4; kt++) {
    const int slot = ((kt * 4 + quad) ^ (c & 7)) * 8;
#pragma unroll
    for (int mt = 0; mt < 4; mt++) {
      bf16x8 kf = *(const bf16x8*)(&Ks[(mt * 16 + c) * 128 + slot]);
      sacc[mt] = __builtin_amdgcn_mfma_f32_16x16x32_bf16(kf, qf[kt], sacc[mt], 0, 0, 0);
    }
  }
  if (diag) {
    const int qg = qbase + c;
#pragma unroll
    for (int mt = 0; mt < 4; mt++)
#pragma unroll
      for (int r = 0; r < 4; r++)
        if (kb + mt * 16 + quad * 4 + r > qg) sacc[mt][r] = -INFINITY;
  }
  float mx = sacc[0][0];
#pragma unroll
  for (int mt = 0; mt < 4; mt++)
#pragma unroll
    for (int r = 0; r < 4; r++) mx = fmaxf(mx, sacc[mt][r]);
  mx = fmaxf(mx, __shfl_xor(mx, 16, 64));
  mx = fmaxf(mx, __shfl_xor(mx, 32, 64));
  const float mnew = fmaxf(m_i, mx);
  const float alpha = exp2f(m_i - mnew);
  m_i = mnew;
  float rs = 0.f;
#pragma unroll
  for (int mt = 0; mt < 4; mt++) {
    float p0 = exp2f(sacc[mt][0] - mnew);
    float p1 = exp2f(sacc[mt][1] - mnew);
    float p2 = exp2f(sacc[mt][2] - mnew);
    float p3 = exp2f(sacc[mt][3] - mnew);
    rs += (p0 + p1) + (p2 + p3);
    // cheap f32->bf16 pack: round-half (+0x8000) then byte-select high16s
    unsigned u0 = __builtin_bit_cast(unsigned, p0) + 0x8000u;
    unsigned u1 = __builtin_bit_cast(unsigned, p1) + 0x8000u;
    unsigned u2 = __builtin_bit_cast(unsigned, p2) + 0x8000u;
    unsigned u3 = __builtin_bit_cast(unsigned, p3) + 0x8000u;
    uint2 pk;
    pk.x = __builtin_amdgcn_perm(u1, u0, 0x07060302u);
    pk.y = __builtin_amdgcn_perm(u3, u2, 0x07060302u);
    *(uint2*)(&Psw[c * 72 + mt * 16 + quad * 4]) = pk;
  }
  rs += __shfl_xor(rs, 16, 64);
  rs += __shfl_xor(rs, 32, 64);
  l_i = l_i * alpha + rs;
  if (__any(alpha != 1.0f)) {
    float a0 = __shfl(alpha, quad * 4 + 0, 64);
    float a1 = __shfl(alpha, quad * 4 + 1, 64);
    float a2 = __shfl(alpha, quad * 4 + 2, 64);
    float a3 = __shfl(alpha, quad * 4 + 3, 64);
#pragma unroll
    for (int nt = 0; nt < 8; nt++) {
      o[nt][0] *= a0; o[nt][1] *= a1; o[nt][2] *= a2; o[nt][3] *= a3;
    }
  }
#pragma unroll
  for (int kk = 0; kk < 2; kk++) {
    bf16x8 pf = *(const bf16x8*)(&Psw[c * 72 + kk * 32 + quad * 8]);
    const int slot = ((kk * 4 + quad) ^ (c & 7)) * 8;
#pragma unroll
    for (int nt = 0; nt < 8; nt++) {
      bf16x8 vf = *(const bf16x8*)(&Vs[(nt * 16 + c) * 64 + slot]);
      o[nt] = __builtin_amdgcn_mfma_f32_16x16x32_bf16(pf, vf, o[nt], 0, 0, 0);
    }
  }
}

__global__ __launch_bounds__(256) void attn_kernel(const bf16* __restrict__ Q,
                                                   const bf16* __restrict__ Kr,
                                                   const bf16* __restrict__ Vt,
                                                   float* __restrict__ O) {
  __shared__ __align__(16) bf16 Ks[64 * 128];
  __shared__ __align__(16) bf16 Vs[128 * 64];
  __shared__ __align__(16) bf16 Ps[4][16 * 72];

  const int tid = threadIdx.x, lane = tid & 63, wave = tid >> 6;
  const int quad = lane >> 4, c = lane & 15;
  const int j = blockIdx.x;                 // pair index 0..15
  const int bh = blockIdx.y;
  const int b = bh >> 4, h = bh & 15, kv = h >> 2;
  bf16* Psw = &Ps[wave][0];

  const bf16* kbase = Kr + (size_t)(b * NKV_ + kv) * S_ * HD_;
  const bf16* vbase = Vt + (size_t)(b * NKV_ + kv) * HD_ * S_;

  // staging offsets (elements)
  int koff[4], voff;
  {
    const int kl = lane >> 4;       // row-in-group for K (4 rows/inst)
    const int ks = lane & 15;
#pragma unroll
    for (int i = 0; i < 4; i++) {
      int r = wave * 16 + i * 4 + kl;
      koff[i] = r * HD_ + ((ks ^ (r & 7)) * 8);
    }
    const int vl = lane >> 3;       // row-in-group for V (8 rows/inst)
    const int vs = lane & 7;
    voff = (wave * 32 + vl) * S_ + ((vs ^ (vl & 7)) * 8);
  }

  // two sequential passes: tile j (pass 0), tile 31-j (pass 1).
  // uniform total work per block: (j+1) + (32-j) = 33 tile-steps.
#pragma unroll 1
  for (int pass = 0; pass < 2; ++pass) {
    const int qt = pass ? (31 - j) : j;
    const int q0 = qt * 64;
    const int qb = q0 + wave * 16;

    bf16x8 qf[4];
    {
      const bf16* qp = Q + ((size_t)(b * NH_ + h) * S_ + qb + c) * HD_;
#pragma unroll
      for (int kt = 0; kt < 4; kt++)
        qf[kt] = *(const bf16x8*)(qp + kt * 32 + quad * 8);
    }
    f32x4 o_acc[8] = {};
    float m_i = -INFINITY, l_i = 0.f;

#pragma unroll 1
    for (int it = 0; it <= qt; ++it) {
      const int kb = it * 64;
      __syncthreads();
#pragma unroll
      for (int i = 0; i < 4; i++) {
        ASYNC_CP16(kbase + (size_t)kb * HD_ + koff[i], &Ks[(wave * 16 + i * 4) * 128]);
        ASYNC_CP16(vbase + kb + voff + (size_t)(i * 8) * S_, &Vs[(wave * 32 + i * 8) * 64]);
      }
      __syncthreads();
      attn_step(Ks, Vs, Psw, qf, o_acc, m_i, l_i, it == qt, kb, qb, quad, c);
    }

    // epilogue
    float inv[4];
#pragma unroll
    for (int r = 0; r < 4; r++) inv[r] = 1.0f / __shfl(l_i, quad * 4 + r, 64);
    float* obase = O + (size_t)b * S_ * D_ + (size_t)h * HD_;
#pragma unroll
    for (int nt = 0; nt < 8; nt++)
#pragma unroll
      for (int r = 0; r < 4; r++)
        obase[(size_t)(qb + quad * 4 + r) * D_ + nt * 16 + c] = o_acc[nt][r] * inv[r];
  }
}

// ---------------- host launch ----------------
extern "C" void kernel_launch(void* const* d_in, const int* in_sizes, int n_in,
                              void* d_out, int out_size, void* d_ws, size_t ws_size,
                              hipStream_t stream) {
  const float* x    = (const float*)d_in[0];
  const float* cosp = (const float*)d_in[1];
  const float* sinp = (const float*)d_in[2];
  const float* wq   = (const float*)d_in[3];
  const float* wk   = (const float*)d_in[4];
  const float* wv   = (const float*)d_in[5];
  float* out = (float*)d_out;

  char* ws = (char*)d_ws;
  const size_t MB = 1024 * 1024;
  bf16* xb    = (bf16*)(ws + 0);         // 32MB
  bf16* wqkvb = (bf16*)(ws + 32 * MB);   // 12MB: [3072, 2048] concat
  bf16* qr    = (bf16*)(ws + 44 * MB);   // 32MB
  bf16* kr    = (bf16*)(ws + 76 * MB);   // 8MB
  bf16* vlin  = (bf16*)(ws + 84 * MB);   // 8MB
  bf16* vt    = (bf16*)(ws + 92 * MB);   // 8MB

  cvt_kernel<<<16384, 256, 0, stream>>>(x, xb, 4194304);
  cvt_kernel<<<4096, 256, 0, stream>>>(wq, wqkvb, 1048576);
  cvt_kernel<<<1024, 256, 0, stream>>>(wk, wqkvb + 4194304, 262144);
  cvt_kernel<<<1024, 256, 0, stream>>>(wv, wqkvb + 5242880, 262144);

  const float qscale = 1.4426950408889634f / 11.313708498984761f;
  gemm_qkv<<<dim3(64, 24), 256, 0, stream>>>(xb, wqkvb, qr, kr, vlin,
                                             cosp, sinp, qscale);

  v_transpose<<<512, 256, 0, stream>>>(vlin, NKV_ * HD_, vt);

  attn_kernel<<<dim3(16, 64), 256, 0, stream>>>(qr, kr, vt, out);
}

// Round 5
// 388.085 us; speedup vs baseline: 1.6864x; 1.0983x over previous
//
#include <hip/hip_runtime.h>
#include <hip/hip_bf16.h>
#include <math.h>

#define B_ 4
#define S_ 2048
#define D_ 2048
#define NH_ 16
#define NKV_ 4
#define HD_ 128

typedef short bf16x8 __attribute__((ext_vector_type(8)));
typedef float f32x4 __attribute__((ext_vector_type(4)));
typedef unsigned u32x4 __attribute__((ext_vector_type(4)));
typedef __hip_bfloat16 bf16;

// async 16B/lane global->LDS: lds dest = uniform base + lane*16
#define ASYNC_CP16(gp, lp)                                                    \
  __builtin_amdgcn_global_load_lds(                                           \
      (const __attribute__((address_space(1))) unsigned int*)(gp),            \
      (__attribute__((address_space(3))) unsigned int*)(lp), 16, 0, 0)

// ---------------- f32 -> bf16 conversion (4 elems/thread) ----------------
__global__ __launch_bounds__(256) void cvt_kernel(const float* __restrict__ in,
                                                  bf16* __restrict__ out, int n4) {
  int i = blockIdx.x * 256 + threadIdx.x;
  if (i >= n4) return;
  float4 v = ((const float4*)in)[i];
  union { ushort4 u; bf16 h[4]; } o;
  o.h[0] = __float2bfloat16(v.x);
  o.h[1] = __float2bfloat16(v.y);
  o.h[2] = __float2bfloat16(v.z);
  o.h[3] = __float2bfloat16(v.w);
  ((ushort4*)out)[i] = o.u;
}

// ---------------- fused QKV GEMM + RoPE epilogue ----------------
// C[8192,3072] = x @ W^T. 128x128 tile, BK=64, 64x64 wave tiles (m97 core).
// hblk 0..15 -> Q head (rope+scale), 16..19 -> K head (rope), 20..23 -> V.
// RoPE needs (d, d+64) pairs which span waves {0,1} x {2,3}; waves 2,3 dump
// their f32 halves to LDS scratch (reusing As/Bs) and waves 0,1 combine.
__global__ __launch_bounds__(256) void gemm_qkv(
    const bf16* __restrict__ A, const bf16* __restrict__ W,
    bf16* __restrict__ qr, bf16* __restrict__ kr, bf16* __restrict__ vlin,
    const float* __restrict__ cosp, const float* __restrict__ sinp,
    float qscale) {
  __shared__ __align__(16) bf16 As[128 * 64];
  __shared__ __align__(16) bf16 Bs[128 * 64];
  const int tid = threadIdx.x;
  const int lane = tid & 63, wave = tid >> 6;
  const int wm = (wave & 1) * 64, wn = (wave >> 1) * 64;
  const int m0 = blockIdx.x * 128;
  const int hblk = blockIdx.y;
  const int n0 = hblk * 128;
  const int quad = lane >> 4, c = lane & 15;
  const int K = 2048;

  f32x4 acc[4][4] = {};

  const int sr = lane >> 3;          // row within 8-row group
  const int sg = lane & 7;           // lds slot within row
  const int gc = (sg ^ sr) * 8;      // swizzled global col group
  const bf16* Ap = A + (size_t)(m0 + wave * 32 + sr) * K + gc;
  const bf16* Bp = W + (size_t)(n0 + wave * 32 + sr) * K + gc;

  for (int kb = 0; kb < K; kb += 64) {
    __syncthreads();
#pragma unroll
    for (int i = 0; i < 4; i++) {
      ASYNC_CP16(Ap + (size_t)(i * 8) * K + kb, &As[(wave * 32 + i * 8) * 64]);
      ASYNC_CP16(Bp + (size_t)(i * 8) * K + kb, &Bs[(wave * 32 + i * 8) * 64]);
    }
    __syncthreads();
#pragma unroll
    for (int kk = 0; kk < 2; kk++) {
      const int slot = ((kk * 4 + quad) ^ (c & 7)) * 8;
      bf16x8 af[4], bfr[4];
#pragma unroll
      for (int t = 0; t < 4; t++) {
        af[t]  = *(const bf16x8*)(&As[(wm + t * 16 + c) * 64 + slot]);
        bfr[t] = *(const bf16x8*)(&Bs[(wn + t * 16 + c) * 64 + slot]);
      }
#pragma unroll
      for (int mt = 0; mt < 4; mt++)
#pragma unroll
        for (int nt = 0; nt < 4; nt++)
          acc[mt][nt] = __builtin_amdgcn_mfma_f32_16x16x32_bf16(
              af[mt], bfr[nt], acc[mt][nt], 0, 0, 0);
    }
  }

  if (hblk >= 20) {
    // V: direct write to vlin[8192, 512]
    const int colb = (hblk - 20) * 128 + wn;
#pragma unroll
    for (int mt = 0; mt < 4; mt++)
#pragma unroll
      for (int reg = 0; reg < 4; reg++) {
        int m = m0 + wm + mt * 16 + quad * 4 + reg;
        bf16* row = vlin + (size_t)m * (NKV_ * HD_) + colb;
#pragma unroll
        for (int nt = 0; nt < 4; nt++)
          row[nt * 16 + c] = __float2bfloat16(acc[mt][nt][reg]);
      }
  } else {
    // RoPE: waves 2,3 (cols 64..127) dump f32 to scratch; waves 0,1 combine.
    float* Sc = (float*)As;  // 128 rows x 64 cols f32 = 32 KB (As+Bs)
    __syncthreads();
    if (wave >= 2) {
#pragma unroll
      for (int mt = 0; mt < 4; mt++)
#pragma unroll
        for (int reg = 0; reg < 4; reg++) {
          int lr = wm + mt * 16 + quad * 4 + reg;
#pragma unroll
          for (int nt = 0; nt < 4; nt++)
            Sc[lr * 64 + nt * 16 + c] = acc[mt][nt][reg];
        }
    }
    __syncthreads();
    if (wave < 2) {
      const float scale = (hblk < 16) ? qscale : 1.0f;
#pragma unroll
      for (int mt = 0; mt < 4; mt++)
#pragma unroll
        for (int reg = 0; reg < 4; reg++) {
          int lr = wm + mt * 16 + quad * 4 + reg;
          int m = m0 + lr;
          int b = m >> 11, s = m & 2047;
          const float* cr = cosp + s * HD_;
          const float* sn = sinp + s * HD_;
          bf16* orow = (hblk < 16)
              ? qr + ((size_t)(b * NH_ + hblk) * S_ + s) * HD_
              : kr + ((size_t)(b * NKV_ + (hblk - 16)) * S_ + s) * HD_;
#pragma unroll
          for (int nt = 0; nt < 4; nt++) {
            int d1 = nt * 16 + c, d2 = d1 + 64;
            float q1 = acc[mt][nt][reg];
            float q2 = Sc[lr * 64 + d1];
            float o1 = (q1 * cr[d1] - q2 * sn[d1]) * scale;
            float o2 = (q2 * cr[d2] + q1 * sn[d2]) * scale;
            orow[d1] = __float2bfloat16(o1);
            orow[d2] = __float2bfloat16(o2);
          }
        }
    }
  }
}

// ---------------- V transpose: vlin[B*S, 512] -> [B,NKV,HD,S] -----
__global__ __launch_bounds__(256) void v_transpose(const bf16* __restrict__ in,
                                                   int instride,
                                                   bf16* __restrict__ out) {
  __shared__ __align__(16) bf16 tile[64][HD_ + 8];
  int bidx = blockIdx.x;
  int st = bidx & 31;
  int kv = (bidx >> 5) & 3;
  int b = bidx >> 7;
  int s0 = st * 64;
  int t = threadIdx.x;
  {
    int row = t >> 2;
    int colb = (t & 3) * 32;
#pragma unroll
    for (int i = 0; i < 4; i++) {
      int col = colb + i * 8;
      *(uint4*)(&tile[row][col]) = *(const uint4*)(
          &in[(size_t)(b * S_ + s0 + row) * instride + kv * HD_ + col]);
    }
  }
  __syncthreads();
  int sl = t & 63, hb = t >> 6;
#pragma unroll
  for (int i = 0; i < 32; i++) {
    int hd = i * 4 + hb;
    out[((size_t)(b * NKV_ + kv) * HD_ + hd) * S_ + s0 + sl] = tile[sl][hd];
  }
}

// ---------------- Flash attention, paired causal tiles (sequential) --------
// S^T = K*Q^T so each lane owns ONE q (q = lane&15): in-lane softmax.
// P staged in XOR-swizzled LDS, stride 64 (no pad): slot sw=mt*4+quad (8B
// units), pair-slot p=sw>>1 swizzled by c&7; PV reads pair-slot kk*4+quad.
__device__ __forceinline__ void attn_step(
    const bf16* __restrict__ Ks, const bf16* __restrict__ Vs,
    bf16* __restrict__ Psw, const bf16x8* qf, f32x4* o,
    float& m_i, float& l_i, bool diag, int kb, int qbase, int quad, int c) {
  f32x4 sacc[4] = {};
#pragma unroll
  for (int kt = 0; kt < 4; kt++) {
    const int slot = ((kt * 4 + quad) ^ (c & 7)) * 8;
#pragma unroll
    for (int mt = 0; mt < 4; mt++) {
      bf16x8 kf = *(const bf16x8*)(&Ks[(mt * 16 + c) * 128 + slot]);
      sacc[mt] = __builtin_amdgcn_mfma_f32_16x16x32_bf16(kf, qf[kt], sacc[mt], 0, 0, 0);
    }
  }
  if (diag) {
    const int qg = qbase + c;
#pragma unroll
    for (int mt = 0; mt < 4; mt++)
#pragma unroll
      for (int r = 0; r < 4; r++)
        if (kb + mt * 16 + quad * 4 + r > qg) sacc[mt][r] = -INFINITY;
  }
  // vector max over 4 sacc, then horizontal + cross-quad
  f32x4 mx4 = __builtin_elementwise_max(
      __builtin_elementwise_max(sacc[0], sacc[1]),
      __builtin_elementwise_max(sacc[2], sacc[3]));
  float mx = fmaxf(fmaxf(mx4[0], mx4[1]), fmaxf(mx4[2], mx4[3]));
  mx = fmaxf(mx, __shfl_xor(mx, 16, 64));
  mx = fmaxf(mx, __shfl_xor(mx, 32, 64));
  const float mnew = fmaxf(m_i, mx);
  const float alpha = exp2f(m_i - mnew);
  m_i = mnew;
  const f32x4 mn4 = {mnew, mnew, mnew, mnew};
  f32x4 rs4 = {0.f, 0.f, 0.f, 0.f};
#pragma unroll
  for (int mt = 0; mt < 4; mt++) {
    f32x4 e = sacc[mt] - mn4;
    f32x4 p;
    p[0] = exp2f(e[0]); p[1] = exp2f(e[1]);
    p[2] = exp2f(e[2]); p[3] = exp2f(e[3]);
    rs4 += p;
    // cheap f32->bf16 pack: +0x8000 then byte-select high16s
    u32x4 u = __builtin_bit_cast(u32x4, p) + 0x8000u;
    uint2 pk;
    pk.x = __builtin_amdgcn_perm(u[1], u[0], 0x07060302u);
    pk.y = __builtin_amdgcn_perm(u[3], u[2], 0x07060302u);
    const int pslot = mt * 2 + (quad >> 1);
    *(uint2*)(&Psw[c * 64 + ((pslot ^ (c & 7)) << 3) + (quad & 1) * 4]) = pk;
  }
  float rs = (rs4[0] + rs4[1]) + (rs4[2] + rs4[3]);
  rs += __shfl_xor(rs, 16, 64);
  rs += __shfl_xor(rs, 32, 64);
  l_i = l_i * alpha + rs;
  if (__any(alpha != 1.0f)) {
    f32x4 av;
    av[0] = __shfl(alpha, quad * 4 + 0, 64);
    av[1] = __shfl(alpha, quad * 4 + 1, 64);
    av[2] = __shfl(alpha, quad * 4 + 2, 64);
    av[3] = __shfl(alpha, quad * 4 + 3, 64);
#pragma unroll
    for (int nt = 0; nt < 8; nt++) o[nt] *= av;
  }
#pragma unroll
  for (int kk = 0; kk < 2; kk++) {
    bf16x8 pf = *(const bf16x8*)(&Psw[c * 64 + (((kk * 4 + quad) ^ (c & 7)) << 3)]);
    const int slot = ((kk * 4 + quad) ^ (c & 7)) * 8;
#pragma unroll
    for (int nt = 0; nt < 8; nt++) {
      bf16x8 vf = *(const bf16x8*)(&Vs[(nt * 16 + c) * 64 + slot]);
      o[nt] = __builtin_amdgcn_mfma_f32_16x16x32_bf16(pf, vf, o[nt], 0, 0, 0);
    }
  }
}

__global__ __launch_bounds__(256, 4) void attn_kernel(const bf16* __restrict__ Q,
                                                      const bf16* __restrict__ Kr,
                                                      const bf16* __restrict__ Vt,
                                                      float* __restrict__ O) {
  __shared__ __align__(16) bf16 Ks[64 * 128];   // 16 KB
  __shared__ __align__(16) bf16 Vs[128 * 64];   // 16 KB
  __shared__ __align__(16) bf16 Ps[4][16 * 64]; // 8 KB (swizzled, no pad)

  const int tid = threadIdx.x, lane = tid & 63, wave = tid >> 6;
  const int quad = lane >> 4, c = lane & 15;
  const int j = blockIdx.x;                 // pair index 0..15
  const int bh = blockIdx.y;
  const int b = bh >> 4, h = bh & 15, kv = h >> 2;
  bf16* Psw = &Ps[wave][0];

  const bf16* kbase = Kr + (size_t)(b * NKV_ + kv) * S_ * HD_;
  const bf16* vbase = Vt + (size_t)(b * NKV_ + kv) * HD_ * S_;

  // staging offsets (elements)
  int koff[4], voff;
  {
    const int kl = lane >> 4;       // row-in-group for K (4 rows/inst)
    const int ks = lane & 15;
#pragma unroll
    for (int i = 0; i < 4; i++) {
      int r = wave * 16 + i * 4 + kl;
      koff[i] = r * HD_ + ((ks ^ (r & 7)) * 8);
    }
    const int vl = lane >> 3;       // row-in-group for V (8 rows/inst)
    const int vs = lane & 7;
    voff = (wave * 32 + vl) * S_ + ((vs ^ (vl & 7)) * 8);
  }

  // two sequential passes: tile j then 31-j; uniform 33 tile-steps per block.
#pragma unroll 1
  for (int pass = 0; pass < 2; ++pass) {
    const int qt = pass ? (31 - j) : j;
    const int q0 = qt * 64;
    const int qb = q0 + wave * 16;

    bf16x8 qf[4];
    {
      const bf16* qp = Q + ((size_t)(b * NH_ + h) * S_ + qb + c) * HD_;
#pragma unroll
      for (int kt = 0; kt < 4; kt++)
        qf[kt] = *(const bf16x8*)(qp + kt * 32 + quad * 8);
    }
    f32x4 o_acc[8] = {};
    float m_i = -INFINITY, l_i = 0.f;

#pragma unroll 1
    for (int it = 0; it <= qt; ++it) {
      const int kb = it * 64;
      __syncthreads();
#pragma unroll
      for (int i = 0; i < 4; i++) {
        ASYNC_CP16(kbase + (size_t)kb * HD_ + koff[i], &Ks[(wave * 16 + i * 4) * 128]);
        ASYNC_CP16(vbase + kb + voff + (size_t)(i * 8) * S_, &Vs[(wave * 32 + i * 8) * 64]);
      }
      __syncthreads();
      attn_step(Ks, Vs, Psw, qf, o_acc, m_i, l_i, it == qt, kb, qb, quad, c);
    }

    // epilogue
    float inv[4];
#pragma unroll
    for (int r = 0; r < 4; r++) inv[r] = 1.0f / __shfl(l_i, quad * 4 + r, 64);
    float* obase = O + (size_t)b * S_ * D_ + (size_t)h * HD_;
#pragma unroll
    for (int nt = 0; nt < 8; nt++)
#pragma unroll
      for (int r = 0; r < 4; r++)
        obase[(size_t)(qb + quad * 4 + r) * D_ + nt * 16 + c] = o_acc[nt][r] * inv[r];
  }
}

// ---------------- host launch ----------------
extern "C" void kernel_launch(void* const* d_in, const int* in_sizes, int n_in,
                              void* d_out, int out_size, void* d_ws, size_t ws_size,
                              hipStream_t stream) {
  const float* x    = (const float*)d_in[0];
  const float* cosp = (const float*)d_in[1];
  const float* sinp = (const float*)d_in[2];
  const float* wq   = (const float*)d_in[3];
  const float* wk   = (const float*)d_in[4];
  const float* wv   = (const float*)d_in[5];
  float* out = (float*)d_out;

  char* ws = (char*)d_ws;
  const size_t MB = 1024 * 1024;
  bf16* xb    = (bf16*)(ws + 0);         // 32MB
  bf16* wqkvb = (bf16*)(ws + 32 * MB);   // 12MB: [3072, 2048] concat
  bf16* qr    = (bf16*)(ws + 44 * MB);   // 32MB
  bf16* kr    = (bf16*)(ws + 76 * MB);   // 8MB
  bf16* vlin  = (bf16*)(ws + 84 * MB);   // 8MB
  bf16* vt    = (bf16*)(ws + 92 * MB);   // 8MB

  cvt_kernel<<<16384, 256, 0, stream>>>(x, xb, 4194304);
  cvt_kernel<<<4096, 256, 0, stream>>>(wq, wqkvb, 1048576);
  cvt_kernel<<<1024, 256, 0, stream>>>(wk, wqkvb + 4194304, 262144);
  cvt_kernel<<<1024, 256, 0, stream>>>(wv, wqkvb + 5242880, 262144);

  const float qscale = 1.4426950408889634f / 11.313708498984761f;
  gemm_qkv<<<dim3(64, 24), 256, 0, stream>>>(xb, wqkvb, qr, kr, vlin,
                                             cosp, sinp, qscale);

  v_transpose<<<512, 256, 0, stream>>>(vlin, NKV_ * HD_, vt);

  attn_kernel<<<dim3(16, 64), 256, 0, stream>>>(qr, kr, vt, out);
}